// Round 14
// baseline (56.759 us; speedup 1.0000x reference)
//
#include <hip/hip_runtime.h>

// LocalL1Loss: out = mean_{n,h,w} min_{7x7 shift} mean_c |in - shifted(tgt, zero-pad)|
// inputs/targets: (16, 3, 512, 512) fp32. Output: scalar fp32.
// R13: R12 + forced-register di-body. One asm block per di does all 6
// ds_read_b128 (3ch x 32B) into six early-clobber u32x4 outputs + lgkmcnt(0);
// the 24 row-dwords are then provably VGPR-resident across the 28 (dj,p) uses,
// killing the compiler's per-use LDS re-read (R7's pins couldn't force
// SIMULTANEOUS liveness; VGPR=32 with a 45-dword live set proved re-reads).
// launch_bounds(512,8): VGPR cap 64, forced set ~50. Tripwire: WRITE_SIZE.

constexpr int N = 16, C = 3, H = 512, W = 512;
constexpr int K = 7, HALO = 3;
constexpr int TH = 64, TW = 64;          // output tile per block
constexpr int SM_ROWS = TH + 2 * HALO;   // 70
constexpr int SM_D = 36;                 // dwords/row: halves [w0-4 .. w0+67]
constexpr int BLK = 512;                 // 64 rows x 8 strips of 8 = 8 waves
constexpr int TOTAL = C * SM_ROWS * SM_D;            // 7560 = 14*512 + 392
// LDS byte strides for the asm offsets
constexpr int CH_B  = SM_ROWS * SM_D * 4;            // 10080
constexpr int ROW_B = SM_D * 4;                      // 144

typedef _Float16 h2 __attribute__((ext_vector_type(2)));
typedef unsigned u32x4 __attribute__((ext_vector_type(4)));
__device__ inline h2 u2h(unsigned u) { return __builtin_bit_cast(h2, u); }
__device__ inline h2 habs2(h2 x) {
    unsigned u = __builtin_bit_cast(unsigned, x) & 0x7fff7fffu;
    return __builtin_bit_cast(h2, u);
}
__device__ inline unsigned f2pk(float a, float b) {
    h2 v; v[0] = (_Float16)a; v[1] = (_Float16)b;
    return __builtin_bit_cast(unsigned, v);
}

__global__ __launch_bounds__(BLK, 8)
void local_l1_kernel(const float* __restrict__ inputs,
                     const float* __restrict__ targets,
                     float* __restrict__ out) {
    __shared__ unsigned sm_u[TOTAL];     // 30,240 B -> 4 blocks/CU (wave cap)

    const int tid = threadIdx.x;
    const int w0 = blockIdx.x * TW;
    const int h0 = blockIdx.y * TH;
    const int n  = blockIdx.z;

    const int tx = tid & 7;    // strip index (w)
    const int ty = tid >> 3;   // row in tile (0..63)

    // ---- issue input loads FIRST so they overlap the staging burst ----
    const float* ibase = inputs + ((size_t)n * C * H + (size_t)(h0 + ty)) * W
                       + (w0 + tx * 8);
    float4 ia[3], ib[3];
    #pragma unroll
    for (int c = 0; c < 3; ++c) {
        ia[c] = *reinterpret_cast<const float4*>(ibase + (size_t)c * H * W);
        ib[c] = *reinterpret_cast<const float4*>(ibase + (size_t)c * H * W + 4);
    }

    // ---- stage targets tile into LDS as packed f16 (R12 batched form) ----
    const float* tbase = targets + (size_t)n * C * H * W;
    const bool interior = (h0 != 0) && (h0 != H - TH) && (w0 != 0) && (w0 != W - TW);
    {
        int rr = tid / SM_D;
        int d2 = tid - rr * SM_D;
        int r  = rr;
        int c  = 0;
        const int f2base = w0 / 2 - 2;    // float2 index of d2=0

        if (interior) {
            #pragma unroll
            for (int g = 0; g < 4; ++g) {
                const int B = (g < 3) ? 4 : 2;
                float2 v[4]; int idx[4];
                #pragma unroll
                for (int b = 0; b < B; ++b) {
                    const int gr = h0 + r - HALO;
                    v[b] = reinterpret_cast<const float2*>(
                        tbase + ((size_t)c * H + gr) * W)[f2base + d2];
                    idx[b] = rr * SM_D + d2;
                    rr += 14; r += 14; d2 += 8;        // step 512 = 14*36 + 8
                    if (d2 >= SM_D) { d2 -= SM_D; rr += 1; r += 1; }
                    if (r >= SM_ROWS) { r -= SM_ROWS; c += 1; }
                }
                #pragma unroll
                for (int b = 0; b < B; ++b)
                    sm_u[idx[b]] = f2pk(v[b].x, v[b].y);
            }
            if (tid < TOTAL - 14 * BLK) {              // tail: 392 threads
                const int gr = h0 + r - HALO;
                float2 v2 = reinterpret_cast<const float2*>(
                    tbase + ((size_t)c * H + gr) * W)[f2base + d2];
                sm_u[rr * SM_D + d2] = f2pk(v2.x, v2.y);
            }
        } else {
            #pragma unroll
            for (int it = 0; it < 15; ++it) {
                if (it < 14 || tid < TOTAL - 14 * BLK) {
                    const int gr = h0 + r - HALO;
                    const int gc = w0 - 4 + 2 * d2;
                    float f0 = 0.0f, f1 = 0.0f;
                    if ((unsigned)gr < (unsigned)H) {
                        const float* rowp = tbase + ((size_t)c * H + gr) * W;
                        if ((unsigned)gc       < (unsigned)W) f0 = rowp[gc];
                        if ((unsigned)(gc + 1) < (unsigned)W) f1 = rowp[gc + 1];
                    }
                    sm_u[rr * SM_D + d2] = f2pk(f0, f1);
                }
                rr += 14; r += 14; d2 += 8;
                if (d2 >= SM_D) { d2 -= SM_D; rr += 1; r += 1; }
                if (r >= SM_ROWS) { r -= SM_ROWS; c += 1; }
            }
        }
    }

    // convert inputs while staging drains
    h2 in_pk[3][4];
    #pragma unroll
    for (int c = 0; c < 3; ++c) {
        in_pk[c][0][0] = (_Float16)ia[c].x; in_pk[c][0][1] = (_Float16)ia[c].y;
        in_pk[c][1][0] = (_Float16)ia[c].z; in_pk[c][1][1] = (_Float16)ia[c].w;
        in_pk[c][2][0] = (_Float16)ib[c].x; in_pk[c][2][1] = (_Float16)ib[c].y;
        in_pk[c][3][0] = (_Float16)ib[c].z; in_pk[c][3][1] = (_Float16)ib[c].w;
    }
    __syncthreads();

    // ---- main loop: 8 outputs/thread, packed pairs, even/odd-dj split ----
    h2 bestA[4], bestB[4];
    #pragma unroll
    for (int p = 0; p < 4; ++p) { bestA[p] = u2h(0x7bff7bffu); bestB[p] = u2h(0x7bff7bffu); }

    // LDS byte address of this thread's row window (c folded into offset:)
    unsigned addr = (unsigned)(size_t)(&sm_u[0]) + (unsigned)(ty * ROW_B + tx * 16);

    #pragma unroll
    for (int di = 0; di < K; ++di) {
        // one asm block: 6x ds_read_b128 -> 24 dwords forced into VGPRs
        u32x4 q0l, q0h, q1l, q1h, q2l, q2h;
        asm volatile(
            "ds_read_b128 %0, %6 offset:0\n\t"
            "ds_read_b128 %1, %6 offset:16\n\t"
            "ds_read_b128 %2, %6 offset:10080\n\t"
            "ds_read_b128 %3, %6 offset:10096\n\t"
            "ds_read_b128 %4, %6 offset:20160\n\t"
            "ds_read_b128 %5, %6 offset:20176\n\t"
            "s_waitcnt lgkmcnt(0)"
            : "=&v"(q0l), "=&v"(q0h), "=&v"(q1l), "=&v"(q1h), "=&v"(q2l), "=&v"(q2h)
            : "v"(addr));
        addr += ROW_B;

        unsigned t2[3][8];
        #pragma unroll
        for (int m = 0; m < 4; ++m) {
            t2[0][m] = q0l[m]; t2[0][m + 4] = q0h[m];
            t2[1][m] = q1l[m]; t2[1][m + 4] = q1h[m];
            t2[2][m] = q2l[m]; t2[2][m + 4] = q2h[m];
        }
        unsigned s[3][7];
        #pragma unroll
        for (int c = 0; c < 3; ++c)
            #pragma unroll
            for (int m = 0; m < 7; ++m)
                s[c][m] = __builtin_amdgcn_alignbit(t2[c][m + 1], t2[c][m], 16);

        #pragma unroll
        for (int dj = 0; dj < K; ++dj) {
            #pragma unroll
            for (int p = 0; p < 4; ++p) {
                h2 w0h, w1h, w2h;
                if (dj & 1) {
                    const int m = p + (dj + 1) / 2;
                    w0h = u2h(t2[0][m]); w1h = u2h(t2[1][m]); w2h = u2h(t2[2][m]);
                } else {
                    const int m = p + dj / 2;
                    w0h = u2h(s[0][m]); w1h = u2h(s[1][m]); w2h = u2h(s[2][m]);
                }
                h2 a0 = habs2(in_pk[0][p] - w0h);
                h2 a1 = habs2(in_pk[1][p] - w1h);
                h2 a2 = habs2(in_pk[2][p] - w2h);
                h2 d  = a0 + a1 + a2;
                if (dj & 1) bestB[p] = __builtin_elementwise_min(bestB[p], d);
                else        bestA[p] = __builtin_elementwise_min(bestA[p], d);
            }
        }
    }

    float part = 0.0f;
    #pragma unroll
    for (int p = 0; p < 4; ++p) {
        h2 b = __builtin_elementwise_min(bestA[p], bestB[p]);
        part += (float)b[0] + (float)b[1];
    }

    // wave (64-lane) reduction, then cross-wave via LDS
    #pragma unroll
    for (int off = 32; off > 0; off >>= 1)
        part += __shfl_down(part, off, 64);

    __shared__ float wsum[BLK / 64];
    if ((tid & 63) == 0) wsum[tid >> 6] = part;
    __syncthreads();
    if (tid == 0) {
        float total = 0.0f;
        #pragma unroll
        for (int i = 0; i < BLK / 64; ++i) total += wsum[i];
        atomicAdd(out, total * (1.0f / (3.0f * (float)N * (float)H * (float)W)));
    }
}

extern "C" void kernel_launch(void* const* d_in, const int* in_sizes, int n_in,
                              void* d_out, int out_size, void* d_ws, size_t ws_size,
                              hipStream_t stream) {
    const float* inputs  = (const float*)d_in[0];
    const float* targets = (const float*)d_in[1];
    float* out = (float*)d_out;

    (void)hipMemsetAsync(out, 0, sizeof(float), stream);
    dim3 grid(W / TW, H / TH, N);
    local_l1_kernel<<<grid, BLK, 0, stream>>>(inputs, targets, out);
}